// Round 2
// baseline (1384.279 us; speedup 1.0000x reference)
//
#include <hip/hip_runtime.h>
#include <hip/hip_bf16.h>

// HyperPatchInvertedResidual: per-patch hyper-conv pipeline with global BNs.
// b=16, c=32, H=W=128, 8x8 patches of 16x16 (+1 halo -> 18x18), HID=192.
// G = 16*64 = 1024 groups.

#define HID 192
#define SP1 324   // 18*18
#define SP2 256   // 16*16
#define HPAR 14016
#define R1 6144   // 32*192
#define R2 7872   // R1 + 192*9
#define NGRP 1024

typedef __hip_bfloat16 bf16;

// ---------------- K1: stage1 1x1 conv 32->192 on 18x18 patch + stats --------
__global__ __launch_bounds__(384) void k1_stage1(
    const float* __restrict__ x, const float* __restrict__ s,
    bf16* __restrict__ y1, float* __restrict__ sum1, float* __restrict__ sq1) {
  int g = blockIdx.x;
  int bi = g >> 6, fi = (g >> 3) & 7, fj = g & 7;
  __shared__ __align__(16) float w1s[6144];   // transposed: [ci*192 + o]
  __shared__ bf16 patch[32 * SP1 + 64];       // [ci*324 + sp]
  int tid = threadIdx.x;
  const float* sg = s + (size_t)bi * HPAR * 64 + fi * 8 + fj;
  for (int k = tid; k < 6144; k += 384) {
    int ci = k / 192, o = k - ci * 192;
    w1s[k] = sg[(size_t)(o * 32 + ci) * 64];
  }
  const float* xb = x + (size_t)bi * 32 * 128 * 128;
  for (int idx = tid; idx < 32 * SP1; idx += 384) {
    int ci = idx / SP1, sp = idx - ci * SP1;
    int a = sp / 18, b = sp - a * 18;
    int r = fi * 16 + a - 1; r = r < 0 ? -r : (r > 127 ? 254 - r : r);
    int c = fj * 16 + b - 1; c = c < 0 ? -c : (c > 127 ? 254 - c : c);
    patch[idx] = __float2bfloat16(xb[((size_t)ci * 128 + r) * 128 + c]);
  }
  __syncthreads();
  int wid = tid >> 6, lane = tid & 63;
  bf16* yg = y1 + (size_t)g * HID * SP1;
  const float4* w4 = (const float4*)w1s;
  for (int t = 0; t < 4; ++t) {
    int o0 = wid * 32 + t * 8;
    float acc[8][6];
#pragma unroll
    for (int a = 0; a < 8; ++a)
#pragma unroll
      for (int b = 0; b < 6; ++b) acc[a][b] = 0.f;
    for (int ci = 0; ci < 32; ++ci) {
      float pv[6];
#pragma unroll
      for (int b = 0; b < 6; ++b)
        pv[b] = __bfloat162float(patch[ci * SP1 + b * 64 + lane]);
      float4 wa = w4[(ci * 192 + o0) >> 2];
      float4 wb = w4[((ci * 192 + o0) >> 2) + 1];
      float wk[8] = {wa.x, wa.y, wa.z, wa.w, wb.x, wb.y, wb.z, wb.w};
#pragma unroll
      for (int a = 0; a < 8; ++a)
#pragma unroll
        for (int b = 0; b < 6; ++b) acc[a][b] += wk[a] * pv[b];
    }
#pragma unroll
    for (int a = 0; a < 8; ++a) {
      float s0 = 0.f, s1 = 0.f;
#pragma unroll
      for (int b = 0; b < 6; ++b) {
        int sp = b * 64 + lane;
        if (sp < SP1) {
          yg[(size_t)(o0 + a) * SP1 + sp] = __float2bfloat16(acc[a][b]);
          s0 += acc[a][b];
          s1 += acc[a][b] * acc[a][b];
        }
      }
#pragma unroll
      for (int off = 32; off; off >>= 1) {
        s0 += __shfl_down(s0, off);
        s1 += __shfl_down(s1, off);
      }
      if (lane == 0) {
        atomicAdd(&sum1[o0 + a], s0);
        atomicAdd(&sq1[o0 + a], s1);
      }
    }
  }
}

// ---------------- bn params: scale/shift from sums --------------------------
__global__ void k_bnp(const float* __restrict__ sums, const float* __restrict__ sqs,
                      const float* __restrict__ gamma, const float* __restrict__ beta,
                      float* __restrict__ sc, float* __restrict__ sh,
                      int CH, float invN) {
  int ch = threadIdx.x;
  if (ch >= CH) return;
  float m = sums[ch] * invN;
  float v = sqs[ch] * invN - m * m;
  float scale = gamma[ch] * rsqrtf(v + 1e-5f);
  sc[ch] = scale;
  sh[ch] = beta[ch] - m * scale;
}

// ---------------- K3: bn1+relu6 then 3x3 depthwise (valid) + stats ----------
// 8 channels per chunk, 24 chunks. Thread owns (channel, col, 8-row strip),
// slides a 3x3 register window vertically: 30 LDS reads per 8 outputs.
#define TSTR 325
__global__ __launch_bounds__(256) void k3_dw(
    const bf16* __restrict__ y1, const float* __restrict__ s,
    const float* __restrict__ sc1, const float* __restrict__ sh1,
    bf16* __restrict__ y2, float* __restrict__ sum2, float* __restrict__ sq2) {
  int g = blockIdx.x;
  int bi = g >> 6, fi = (g >> 3) & 7, fj = g & 7;
  const float* sg2 = s + (size_t)bi * HPAR * 64 + fi * 8 + fj + (size_t)R1 * 64;
  __shared__ float tile[8 * TSTR];
  __shared__ float w9s[72];
  int tid = threadIdx.x;
  int ch = tid >> 5, l = tid & 31;
  int col = l & 15, half = l >> 4;
  int r0 = half * 8;
  for (int cc = 0; cc < 24; ++cc) {
    if (cc) __syncthreads();  // protect tile from previous chunk's readers
    // load 8 channels x 324, bn1+relu6 fused, vectorized 2 x bf16
    for (int idx = tid; idx < 1296; idx += 256) {
      int c8 = idx / 162, j = idx - c8 * 162;
      int o = cc * 8 + c8;
      const ushort2* row = (const ushort2*)(y1 + ((size_t)g * HID + o) * SP1);
      ushort2 u = row[j];
      float scv = sc1[o], shv = sh1[o];
      __hip_bfloat16_raw r0b, r1b; r0b.x = u.x; r1b.x = u.y;
      float v0 = __bfloat162float((bf16)r0b) * scv + shv;
      float v1 = __bfloat162float((bf16)r1b) * scv + shv;
      tile[c8 * TSTR + 2 * j]     = fminf(fmaxf(v0, 0.f), 6.f);
      tile[c8 * TSTR + 2 * j + 1] = fminf(fmaxf(v1, 0.f), 6.f);
    }
    if (tid < 72) {
      int c8 = tid / 9, k = tid - c8 * 9;
      w9s[tid] = sg2[(size_t)((cc * 8 + c8) * 9 + k) * 64];
    }
    __syncthreads();
    int o = cc * 8 + ch;
    const float* tch = &tile[ch * TSTR];
    float wk[9];
#pragma unroll
    for (int k = 0; k < 9; ++k) wk[k] = w9s[ch * 9 + k];
    float rp[3], rc[3], rn[3];
#pragma unroll
    for (int j = 0; j < 3; ++j) {
      rp[j] = tch[r0 * 18 + col + j];
      rc[j] = tch[(r0 + 1) * 18 + col + j];
    }
    float s0 = 0.f, s1 = 0.f;
    bf16* yrow = y2 + ((size_t)g * HID + o) * SP2;
#pragma unroll
    for (int rr = 0; rr < 8; ++rr) {
#pragma unroll
      for (int j = 0; j < 3; ++j) rn[j] = tch[(r0 + rr + 2) * 18 + col + j];
      float acc = rp[0] * wk[0] + rp[1] * wk[1] + rp[2] * wk[2]
                + rc[0] * wk[3] + rc[1] * wk[4] + rc[2] * wk[5]
                + rn[0] * wk[6] + rn[1] * wk[7] + rn[2] * wk[8];
      yrow[(r0 + rr) * 16 + col] = __float2bfloat16(acc);
      s0 += acc; s1 += acc * acc;
#pragma unroll
      for (int j = 0; j < 3; ++j) { rp[j] = rc[j]; rc[j] = rn[j]; }
    }
#pragma unroll
    for (int off = 16; off; off >>= 1) {
      s0 += __shfl_down(s0, off, 32);
      s1 += __shfl_down(s1, off, 32);
    }
    if (l == 0) {
      atomicAdd(&sum2[o], s0);
      atomicAdd(&sq2[o], s1);
    }
  }
}

// ---------------- K5: bn2+relu6 then 1x1 conv 192->32 + stats ---------------
__global__ __launch_bounds__(256) void k5_stage3(
    const bf16* __restrict__ y2, const float* __restrict__ s,
    const float* __restrict__ sc2, const float* __restrict__ sh2,
    bf16* __restrict__ y3, float* __restrict__ sum3, float* __restrict__ sq3) {
  int g = blockIdx.x;
  int bi = g >> 6, fi = (g >> 3) & 7, fj = g & 7;
  const float* sg = s + (size_t)bi * HPAR * 64 + fi * 8 + fj;
  __shared__ __align__(16) float w3s[6144];      // [o*32 + o2]
  __shared__ __align__(16) float tile[32 * SP2]; // [oo*256 + sp]
  int tid = threadIdx.x;
  for (int k = tid; k < 6144; k += 256) {
    int o = k >> 5, o2 = k & 31;
    w3s[k] = sg[(size_t)(R2 + o2 * HID + o) * 64];
  }
  float acc[8][4];
#pragma unroll
  for (int a = 0; a < 8; ++a)
#pragma unroll
    for (int b = 0; b < 4; ++b) acc[a][b] = 0.f;
  int wv = tid >> 6;    // 4 waves -> o2 block of 8
  int spg = tid & 63;   // sp group of 4
  const float4* w4 = (const float4*)w3s;
  const float4* t4 = (const float4*)tile;
  for (int oc = 0; oc < 6; ++oc) {
    __syncthreads();
    for (int t = 0; t < 32; ++t) {
      int o = oc * 32 + t;
      float v = __bfloat162float(y2[((size_t)g * HID + o) * SP2 + tid]);
      v = v * sc2[o] + sh2[o];
      tile[t * SP2 + tid] = fminf(fmaxf(v, 0.f), 6.f);
    }
    __syncthreads();
    for (int t = 0; t < 32; ++t) {
      int o = oc * 32 + t;
      float4 tv = t4[t * 64 + spg];
      float4 wa = w4[o * 8 + wv * 2];
      float4 wb = w4[o * 8 + wv * 2 + 1];
      float wk[8] = {wa.x, wa.y, wa.z, wa.w, wb.x, wb.y, wb.z, wb.w};
#pragma unroll
      for (int a = 0; a < 8; ++a) {
        acc[a][0] += wk[a] * tv.x;
        acc[a][1] += wk[a] * tv.y;
        acc[a][2] += wk[a] * tv.z;
        acc[a][3] += wk[a] * tv.w;
      }
    }
  }
#pragma unroll
  for (int a = 0; a < 8; ++a) {
    int o2 = wv * 8 + a;
    float s0 = 0.f, s1 = 0.f;
#pragma unroll
    for (int b = 0; b < 4; ++b) {
      y3[((size_t)g * 32 + o2) * SP2 + spg * 4 + b] = __float2bfloat16(acc[a][b]);
      s0 += acc[a][b];
      s1 += acc[a][b] * acc[a][b];
    }
#pragma unroll
    for (int off = 32; off; off >>= 1) {
      s0 += __shfl_down(s0, off);
      s1 += __shfl_down(s1, off);
    }
    if (spg == 0) {
      atomicAdd(&sum3[o2], s0);
      atomicAdd(&sq3[o2], s1);
    }
  }
}

// ---------------- K7: bn3 + residual + scatter back -------------------------
__global__ __launch_bounds__(256) void k7_out(
    const float* __restrict__ x, const bf16* __restrict__ y3,
    const float* __restrict__ sc3, const float* __restrict__ sh3,
    float* __restrict__ out) {
  int idx = blockIdx.x * 256 + threadIdx.x;  // 16*32*128*128 = 8388608
  int wcol = idx & 127;
  int hrow = (idx >> 7) & 127;
  int o2 = (idx >> 14) & 31;
  int bi = idx >> 19;
  int g = bi * 64 + (hrow >> 4) * 8 + (wcol >> 4);
  float v = __bfloat162float(y3[((size_t)g * 32 + o2) * SP2 + ((hrow & 15) << 4) + (wcol & 15)]);
  out[idx] = x[idx] + v * sc3[o2] + sh3[o2];
}

extern "C" void kernel_launch(void* const* d_in, const int* in_sizes, int n_in,
                              void* d_out, int out_size, void* d_ws, size_t ws_size,
                              hipStream_t stream) {
  const float* x  = (const float*)d_in[0];
  const float* s  = (const float*)d_in[1];
  const float* g1 = (const float*)d_in[2];
  const float* b1 = (const float*)d_in[3];
  const float* g2 = (const float*)d_in[4];
  const float* b2 = (const float*)d_in[5];
  const float* g3 = (const float*)d_in[6];
  const float* b3 = (const float*)d_in[7];
  float* out = (float*)d_out;

  char* ws = (char*)d_ws;
  float* stats = (float*)ws;
  float* sum1 = stats;        float* sq1 = stats + 192;
  float* sum2 = stats + 384;  float* sq2 = stats + 576;
  float* sum3 = stats + 768;  float* sq3 = stats + 800;
  float* sc1 = stats + 1024;  float* sh1 = stats + 1216;
  float* sc2 = stats + 1408;  float* sh2 = stats + 1600;
  float* sc3 = stats + 1792;  float* sh3 = stats + 1824;
  bf16* y1 = (bf16*)(ws + 8192);                       // 1024*192*324 bf16
  bf16* y2 = y1 + (size_t)NGRP * HID * SP1;            // 1024*192*256 bf16
  bf16* y3 = y1;                                       // alias: y1 dead by K5

  hipMemsetAsync(stats, 0, 832 * sizeof(float), stream);

  k1_stage1<<<NGRP, 384, 0, stream>>>(x, s, y1, sum1, sq1);
  k_bnp<<<1, 192, 0, stream>>>(sum1, sq1, g1, b1, sc1, sh1, HID, 1.f / (NGRP * (float)SP1));
  k3_dw<<<NGRP, 256, 0, stream>>>(y1, s, sc1, sh1, y2, sum2, sq2);
  k_bnp<<<1, 192, 0, stream>>>(sum2, sq2, g2, b2, sc2, sh2, HID, 1.f / (NGRP * (float)SP2));
  k5_stage3<<<NGRP, 256, 0, stream>>>(y2, s, sc2, sh2, y3, sum3, sq3);
  k_bnp<<<1, 32, 0, stream>>>(sum3, sq3, g3, b3, sc3, sh3, 32, 1.f / (NGRP * (float)SP2));
  k7_out<<<(16 * 32 * 128 * 128) / 256, 256, 0, stream>>>(x, y3, sc3, sh3, out);
}

// Round 3
// 515.426 us; speedup vs baseline: 2.6857x; 2.6857x over previous
//
#include <hip/hip_runtime.h>
#include <hip/hip_bf16.h>

// HyperPatchInvertedResidual: per-patch hyper-conv pipeline with global BNs.
// b=16, c=32, H=W=128, 8x8 patches of 16x16 (+1 halo -> 18x18), HID=192.
// G = 16*64 = 1024 groups.

#define HID 192
#define SP1 324   // 18*18
#define SP2 256   // 16*16
#define HPAR 14016
#define R1 6144   // 32*192
#define R2 7872   // R1 + 192*9
#define NGRP 1024

typedef __hip_bfloat16 bf16;

// ---------------- K1: stage1 1x1 conv 32->192 on 18x18 patch ----------------
// (round-1 proven version: NO fused stats — rule #20, shuffle epilogues
//  broke unrolling and spilled the accumulator to scratch in round 2)
__global__ __launch_bounds__(384) void k1_stage1(
    const float* __restrict__ x, const float* __restrict__ s,
    bf16* __restrict__ y1) {
  int g = blockIdx.x;
  int bi = g >> 6, fi = (g >> 3) & 7, fj = g & 7;
  __shared__ __align__(16) float w1s[6144];   // transposed: [ci*192 + o]
  __shared__ bf16 patch[32 * SP1 + 64];       // [ci*324 + sp]
  int tid = threadIdx.x;
  const float* sg = s + (size_t)bi * HPAR * 64 + fi * 8 + fj;
  for (int k = tid; k < 6144; k += 384) {
    int ci = k / 192, o = k - ci * 192;
    w1s[k] = sg[(size_t)(o * 32 + ci) * 64];
  }
  const float* xb = x + (size_t)bi * 32 * 128 * 128;
  for (int idx = tid; idx < 32 * SP1; idx += 384) {
    int ci = idx / SP1, sp = idx - ci * SP1;
    int a = sp / 18, b = sp - a * 18;
    int r = fi * 16 + a - 1; r = r < 0 ? -r : (r > 127 ? 254 - r : r);
    int c = fj * 16 + b - 1; c = c < 0 ? -c : (c > 127 ? 254 - c : c);
    patch[idx] = __float2bfloat16(xb[((size_t)ci * 128 + r) * 128 + c]);
  }
  __syncthreads();
  int wid = tid >> 6, lane = tid & 63;
  bf16* yg = y1 + (size_t)g * HID * SP1;
  const float4* w4 = (const float4*)w1s;
  for (int t = 0; t < 4; ++t) {
    int o0 = wid * 32 + t * 8;
    float acc[8][6];
#pragma unroll
    for (int a = 0; a < 8; ++a)
#pragma unroll
      for (int b = 0; b < 6; ++b) acc[a][b] = 0.f;
    for (int ci = 0; ci < 32; ++ci) {
      float pv[6];
#pragma unroll
      for (int b = 0; b < 6; ++b)
        pv[b] = __bfloat162float(patch[ci * SP1 + b * 64 + lane]);
      float4 wa = w4[(ci * 192 + o0) >> 2];
      float4 wb = w4[((ci * 192 + o0) >> 2) + 1];
      float wk[8] = {wa.x, wa.y, wa.z, wa.w, wb.x, wb.y, wb.z, wb.w};
#pragma unroll
      for (int a = 0; a < 8; ++a)
#pragma unroll
        for (int b = 0; b < 6; ++b) acc[a][b] += wk[a] * pv[b];
    }
#pragma unroll
    for (int a = 0; a < 8; ++a)
#pragma unroll
      for (int b = 0; b < 6; ++b) {
        int sp = b * 64 + lane;
        if (sp < SP1) yg[(size_t)(o0 + a) * SP1 + sp] = __float2bfloat16(acc[a][b]);
      }
  }
}

// ---------------- stats: per-channel sum & sumsq over [G][CH][SPL] ----------
__global__ __launch_bounds__(256) void k_stats(
    const bf16* __restrict__ src, int CH, int SPL, int gPerBlk,
    float* __restrict__ sums, float* __restrict__ sqs) {
  int ch = blockIdx.x % CH;
  int g0 = (blockIdx.x / CH) * gPerBlk;
  float s0 = 0.f, s1 = 0.f;
  for (int gg = 0; gg < gPerBlk; ++gg) {
    const bf16* p = src + ((size_t)(g0 + gg) * CH + ch) * SPL;
    for (int sp = threadIdx.x; sp < SPL; sp += 256) {
      float v = __bfloat162float(p[sp]);
      s0 += v; s1 += v * v;
    }
  }
#pragma unroll
  for (int off = 32; off; off >>= 1) {
    s0 += __shfl_down(s0, off);
    s1 += __shfl_down(s1, off);
  }
  __shared__ float red[8];
  int lane = threadIdx.x & 63, wid = threadIdx.x >> 6;
  if (lane == 0) { red[wid] = s0; red[4 + wid] = s1; }
  __syncthreads();
  if (threadIdx.x == 0) {
    float a = red[0] + red[1] + red[2] + red[3];
    float b = red[4] + red[5] + red[6] + red[7];
    atomicAdd(&sums[ch], a);
    atomicAdd(&sqs[ch], b);
  }
}

// ---------------- bn params: scale/shift from sums --------------------------
__global__ void k_bnp(const float* __restrict__ sums, const float* __restrict__ sqs,
                      const float* __restrict__ gamma, const float* __restrict__ beta,
                      float* __restrict__ sc, float* __restrict__ sh,
                      int CH, float invN) {
  int ch = threadIdx.x;
  if (ch >= CH) return;
  float m = sums[ch] * invN;
  float v = sqs[ch] * invN - m * m;
  float scale = gamma[ch] * rsqrtf(v + 1e-5f);
  sc[ch] = scale;
  sh[ch] = beta[ch] - m * scale;
}

// ---------------- K3: bn1+relu6 then 3x3 depthwise (valid) ------------------
// 8 channels per chunk, 24 chunks -> 48 barriers (vs 384 in round 1).
// Thread owns (channel, col, 8-row strip); 3x3 register sliding window.
#define TSTR 325
__global__ __launch_bounds__(256) void k3_dw(
    const bf16* __restrict__ y1, const float* __restrict__ s,
    const float* __restrict__ sc1, const float* __restrict__ sh1,
    bf16* __restrict__ y2) {
  int g = blockIdx.x;
  int bi = g >> 6, fi = (g >> 3) & 7, fj = g & 7;
  const float* sg2 = s + (size_t)bi * HPAR * 64 + fi * 8 + fj + (size_t)R1 * 64;
  __shared__ float tile[8 * TSTR];
  __shared__ float w9s[72];
  int tid = threadIdx.x;
  int ch = tid >> 5, l = tid & 31;
  int col = l & 15, half = l >> 4;
  int r0 = half * 8;
  for (int cc = 0; cc < 24; ++cc) {
    if (cc) __syncthreads();  // protect tile from previous chunk's readers
    for (int idx = tid; idx < 1296; idx += 256) {
      int c8 = idx / 162, j = idx - c8 * 162;
      int o = cc * 8 + c8;
      const ushort2* row = (const ushort2*)(y1 + ((size_t)g * HID + o) * SP1);
      ushort2 u = row[j];
      float scv = sc1[o], shv = sh1[o];
      __hip_bfloat16_raw r0b, r1b; r0b.x = u.x; r1b.x = u.y;
      float v0 = __bfloat162float((bf16)r0b) * scv + shv;
      float v1 = __bfloat162float((bf16)r1b) * scv + shv;
      tile[c8 * TSTR + 2 * j]     = fminf(fmaxf(v0, 0.f), 6.f);
      tile[c8 * TSTR + 2 * j + 1] = fminf(fmaxf(v1, 0.f), 6.f);
    }
    if (tid < 72) {
      int c8 = tid / 9, k = tid - c8 * 9;
      w9s[tid] = sg2[(size_t)((cc * 8 + c8) * 9 + k) * 64];
    }
    __syncthreads();
    int o = cc * 8 + ch;
    const float* tch = &tile[ch * TSTR];
    float wk[9];
#pragma unroll
    for (int k = 0; k < 9; ++k) wk[k] = w9s[ch * 9 + k];
    float rp[3], rc[3], rn[3];
#pragma unroll
    for (int j = 0; j < 3; ++j) {
      rp[j] = tch[r0 * 18 + col + j];
      rc[j] = tch[(r0 + 1) * 18 + col + j];
    }
    bf16* yrow = y2 + ((size_t)g * HID + o) * SP2;
#pragma unroll
    for (int rr = 0; rr < 8; ++rr) {
#pragma unroll
      for (int j = 0; j < 3; ++j) rn[j] = tch[(r0 + rr + 2) * 18 + col + j];
      float acc = rp[0] * wk[0] + rp[1] * wk[1] + rp[2] * wk[2]
                + rc[0] * wk[3] + rc[1] * wk[4] + rc[2] * wk[5]
                + rn[0] * wk[6] + rn[1] * wk[7] + rn[2] * wk[8];
      yrow[(r0 + rr) * 16 + col] = __float2bfloat16(acc);
#pragma unroll
      for (int j = 0; j < 3; ++j) { rp[j] = rc[j]; rc[j] = rn[j]; }
    }
  }
}

// ---------------- K5: bn2+relu6 then 1x1 conv 192->32 -----------------------
__global__ __launch_bounds__(256) void k5_stage3(
    const bf16* __restrict__ y2, const float* __restrict__ s,
    const float* __restrict__ sc2, const float* __restrict__ sh2,
    bf16* __restrict__ y3) {
  int g = blockIdx.x;
  int bi = g >> 6, fi = (g >> 3) & 7, fj = g & 7;
  const float* sg = s + (size_t)bi * HPAR * 64 + fi * 8 + fj;
  __shared__ __align__(16) float w3s[6144];      // [o*32 + o2]
  __shared__ __align__(16) float tile[32 * SP2]; // [oo*256 + sp]
  int tid = threadIdx.x;
  for (int k = tid; k < 6144; k += 256) {
    int o = k >> 5, o2 = k & 31;
    w3s[k] = sg[(size_t)(R2 + o2 * HID + o) * 64];
  }
  float acc[8][4];
#pragma unroll
  for (int a = 0; a < 8; ++a)
#pragma unroll
    for (int b = 0; b < 4; ++b) acc[a][b] = 0.f;
  int wv = tid >> 6;    // 4 waves -> o2 block of 8
  int spg = tid & 63;   // sp group of 4
  const float4* w4 = (const float4*)w3s;
  const float4* t4 = (const float4*)tile;
  for (int oc = 0; oc < 6; ++oc) {
    __syncthreads();
    for (int t = 0; t < 32; ++t) {
      int o = oc * 32 + t;
      float v = __bfloat162float(y2[((size_t)g * HID + o) * SP2 + tid]);
      v = v * sc2[o] + sh2[o];
      tile[t * SP2 + tid] = fminf(fmaxf(v, 0.f), 6.f);
    }
    __syncthreads();
    for (int t = 0; t < 32; ++t) {
      int o = oc * 32 + t;
      float4 tv = t4[t * 64 + spg];
      float4 wa = w4[o * 8 + wv * 2];
      float4 wb = w4[o * 8 + wv * 2 + 1];
      float wk[8] = {wa.x, wa.y, wa.z, wa.w, wb.x, wb.y, wb.z, wb.w};
#pragma unroll
      for (int a = 0; a < 8; ++a) {
        acc[a][0] += wk[a] * tv.x;
        acc[a][1] += wk[a] * tv.y;
        acc[a][2] += wk[a] * tv.z;
        acc[a][3] += wk[a] * tv.w;
      }
    }
  }
#pragma unroll
  for (int a = 0; a < 8; ++a) {
    int o2 = wv * 8 + a;
#pragma unroll
    for (int b = 0; b < 4; ++b)
      y3[((size_t)g * 32 + o2) * SP2 + spg * 4 + b] = __float2bfloat16(acc[a][b]);
  }
}

// ---------------- K7: bn3 + residual + scatter back -------------------------
__global__ __launch_bounds__(256) void k7_out(
    const float* __restrict__ x, const bf16* __restrict__ y3,
    const float* __restrict__ sc3, const float* __restrict__ sh3,
    float* __restrict__ out) {
  int idx = blockIdx.x * 256 + threadIdx.x;  // 16*32*128*128 = 8388608
  int wcol = idx & 127;
  int hrow = (idx >> 7) & 127;
  int o2 = (idx >> 14) & 31;
  int bi = idx >> 19;
  int g = bi * 64 + (hrow >> 4) * 8 + (wcol >> 4);
  float v = __bfloat162float(y3[((size_t)g * 32 + o2) * SP2 + ((hrow & 15) << 4) + (wcol & 15)]);
  out[idx] = x[idx] + v * sc3[o2] + sh3[o2];
}

extern "C" void kernel_launch(void* const* d_in, const int* in_sizes, int n_in,
                              void* d_out, int out_size, void* d_ws, size_t ws_size,
                              hipStream_t stream) {
  const float* x  = (const float*)d_in[0];
  const float* s  = (const float*)d_in[1];
  const float* g1 = (const float*)d_in[2];
  const float* b1 = (const float*)d_in[3];
  const float* g2 = (const float*)d_in[4];
  const float* b2 = (const float*)d_in[5];
  const float* g3 = (const float*)d_in[6];
  const float* b3 = (const float*)d_in[7];
  float* out = (float*)d_out;

  char* ws = (char*)d_ws;
  float* stats = (float*)ws;
  float* sum1 = stats;        float* sq1 = stats + 192;
  float* sum2 = stats + 384;  float* sq2 = stats + 576;
  float* sum3 = stats + 768;  float* sq3 = stats + 800;
  float* sc1 = stats + 1024;  float* sh1 = stats + 1216;
  float* sc2 = stats + 1408;  float* sh2 = stats + 1600;
  float* sc3 = stats + 1792;  float* sh3 = stats + 1824;
  bf16* y1 = (bf16*)(ws + 8192);                       // 1024*192*324 bf16
  bf16* y2 = y1 + (size_t)NGRP * HID * SP1;            // 1024*192*256 bf16
  bf16* y3 = y1;                                       // alias: y1 dead by K5

  hipMemsetAsync(stats, 0, 832 * sizeof(float), stream);

  k1_stage1<<<NGRP, 384, 0, stream>>>(x, s, y1);
  k_stats<<<192 * 64, 256, 0, stream>>>(y1, HID, SP1, 16, sum1, sq1);
  k_bnp<<<1, 192, 0, stream>>>(sum1, sq1, g1, b1, sc1, sh1, HID, 1.f / (NGRP * (float)SP1));
  k3_dw<<<NGRP, 256, 0, stream>>>(y1, s, sc1, sh1, y2);
  k_bnp<<<1, 192, 0, stream>>>(sum2, sq2, g2, b2, sc2, sh2, HID, 1.f / (NGRP * (float)SP2));
  k_stats<<<192 * 64, 256, 0, stream>>>(y2, HID, SP2, 16, sum2, sq2);
  k_bnp<<<1, 192, 0, stream>>>(sum2, sq2, g2, b2, sc2, sh2, HID, 1.f / (NGRP * (float)SP2));
  k5_stage3<<<NGRP, 256, 0, stream>>>(y2, s, sc2, sh2, y3);
  k_stats<<<32 * 64, 256, 0, stream>>>(y3, 32, SP2, 16, sum3, sq3);
  k_bnp<<<1, 32, 0, stream>>>(sum3, sq3, g3, b3, sc3, sh3, 32, 1.f / (NGRP * (float)SP2));
  k7_out<<<(16 * 32 * 128 * 128) / 256, 256, 0, stream>>>(x, y3, sc3, sh3, out);
}